// Round 2
// baseline (500.373 us; speedup 1.0000x reference)
//
#include <hip/hip_runtime.h>
#include <math.h>

#define N_NODES 50000
#define E_EDGES 500000
#define D 32
#define ED 16
// msg layout per buffer: [0..31]=h[row], [32..63]=Q@h[col], [64..79]=edge_attr, [80..111]=hidden
#define MSG_LEN 112

__global__ __launch_bounds__(256) void edge_kernel(
    const float* __restrict__ h, const float* __restrict__ edge_attr,
    const float* __restrict__ Q, const float* __restrict__ W1,
    const float* __restrict__ b1, const float* __restrict__ W2,
    const float* __restrict__ b2, const int* __restrict__ eidx,
    float* __restrict__ agg)
{
    const int lane = threadIdx.x & 63;
    const int wib  = threadIdx.x >> 6;                 // wave in block (0..3)
    const int gwave = blockIdx.x * 4 + wib;
    const int nwaves = gridDim.x * 4;

    const int o   = lane & 31;   // output unit this lane owns
    const int hh  = lane >> 5;   // which half of the reduction dim
    const int g   = lane >> 3;   // Q row group (0..7)
    const int sub = lane & 7;    // Q col chunk within group

    // --- weight columns in registers (W1: 80x32, W2: 32x32) ---
    float w1c[40];
#pragma unroll
    for (int i = 0; i < 40; ++i) w1c[i] = W1[(hh * 40 + i) * D + o];
    float w2c[16];
#pragma unroll
    for (int i = 0; i < 16; ++i) w2c[i] = W2[(hh * 16 + i) * D + o];
    const float b1o = b1[o];
    const float b2o = b2[o];

    __shared__ __align__(16) float msg_s[4][2][MSG_LEN];
    float* m0 = msg_s[wib][0];
    float* m1 = msg_s[wib][1];

    const long long step = 2LL * nwaves;
    long long e0 = 2LL * gwave;          // E is even; e0+1 always valid when e0 < E

    // prefetch first pair's indices (wave-uniform -> scalar loads)
    int2 rowp = *reinterpret_cast<const int2*>(eidx + e0);
    int2 colp = *reinterpret_cast<const int2*>(eidx + E_EDGES + e0);

    for (; e0 < E_EDGES; e0 += step) {
        const long long e1 = e0 + 1;
        const int row0 = rowp.x, row1 = rowp.y;
        const int col0 = colp.x, col1 = colp.y;

        // ---- issue all global loads for this pair up front ----
        const float4 hc0 = *reinterpret_cast<const float4*>(h + (size_t)col0 * D + sub * 4);
        const float4 hc1 = *reinterpret_cast<const float4*>(h + (size_t)col1 * D + sub * 4);

        // stage h[row] and edge_attr via disjoint lane groups (one float4 each)
        if (lane < 8) {
            const float4 hv = *reinterpret_cast<const float4*>(h + (size_t)row0 * D + lane * 4);
            *reinterpret_cast<float4*>(m0 + lane * 4) = hv;
        } else if (lane < 16) {
            const int l = lane - 8;
            const float4 hv = *reinterpret_cast<const float4*>(h + (size_t)row1 * D + l * 4);
            *reinterpret_cast<float4*>(m1 + l * 4) = hv;
        } else if (lane < 20) {
            const int l = lane - 16;
            const float4 ev = *reinterpret_cast<const float4*>(edge_attr + (size_t)e0 * ED + l * 4);
            *reinterpret_cast<float4*>(m0 + 64 + l * 4) = ev;
        } else if (lane < 24) {
            const int l = lane - 20;
            const float4 ev = *reinterpret_cast<const float4*>(edge_attr + (size_t)e1 * ED + l * 4);
            *reinterpret_cast<float4*>(m1 + 64 + l * 4) = ev;
        }

        const float* qe0 = Q + (size_t)e0 * (D * D);
        const float* qe1 = Q + (size_t)e1 * (D * D);
        float4 qa[4], qb[4];
#pragma unroll
        for (int k = 0; k < 4; ++k)
            qa[k] = *reinterpret_cast<const float4*>(qe0 + k * 256 + lane * 4);
#pragma unroll
        for (int k = 0; k < 4; ++k)
            qb[k] = *reinterpret_cast<const float4*>(qe1 + k * 256 + lane * 4);

        // prefetch next pair's indices while Q is in flight
        const long long en = e0 + step;
        if (en < E_EDGES) {
            rowp = *reinterpret_cast<const int2*>(eidx + en);
            colp = *reinterpret_cast<const int2*>(eidx + E_EDGES + en);
        }

        // ---- sheaf transport: acc[k] = (Q h)[row k*8+g] partials over sub ----
        float acc0[4], acc1[4];
#pragma unroll
        for (int k = 0; k < 4; ++k) {
            acc0[k] = qa[k].x * hc0.x + qa[k].y * hc0.y + qa[k].z * hc0.z + qa[k].w * hc0.w;
            acc1[k] = qb[k].x * hc1.x + qb[k].y * hc1.y + qb[k].z * hc1.z + qb[k].w * hc1.w;
        }
#pragma unroll
        for (int mm = 1; mm <= 4; mm <<= 1) {
#pragma unroll
            for (int k = 0; k < 4; ++k) {
                acc0[k] += __shfl_xor(acc0[k], mm);
                acc1[k] += __shfl_xor(acc1[k], mm);
            }
        }
        if (sub == 0) {
#pragma unroll
            for (int k = 0; k < 4; ++k) {
                m0[D + k * 8 + g] = acc0[k];
                m1[D + k * 8 + g] = acc1[k];
            }
        }
        // same-wave DS ops complete in order; compiler inserts lgkmcnt before use

        // ---- MLP layer 1: hidden[o] = relu(msg . W1[:,o] + b1[o]) ----
        float s0 = 0.f, s1 = 0.f;
        const float4* ma4 = reinterpret_cast<const float4*>(m0 + hh * 40);
        const float4* mb4 = reinterpret_cast<const float4*>(m1 + hh * 40);
#pragma unroll
        for (int i4 = 0; i4 < 10; ++i4) {
            const float4 va = ma4[i4];
            const float4 vb = mb4[i4];
            s0 = fmaf(va.x, w1c[4 * i4 + 0], s0);
            s1 = fmaf(vb.x, w1c[4 * i4 + 0], s1);
            s0 = fmaf(va.y, w1c[4 * i4 + 1], s0);
            s1 = fmaf(vb.y, w1c[4 * i4 + 1], s1);
            s0 = fmaf(va.z, w1c[4 * i4 + 2], s0);
            s1 = fmaf(vb.z, w1c[4 * i4 + 2], s1);
            s0 = fmaf(va.w, w1c[4 * i4 + 3], s0);
            s1 = fmaf(vb.w, w1c[4 * i4 + 3], s1);
        }
        s0 += __shfl_xor(s0, 32);
        s1 += __shfl_xor(s1, 32);
        s0 = fmaxf(s0 + b1o, 0.f);
        s1 = fmaxf(s1 + b1o, 0.f);

        if (lane < 32) m0[80 + o] = s0;
        else           m1[80 + o] = s1;

        // ---- MLP layer 2 ----
        float t0 = 0.f, t1 = 0.f;
        const float4* ha4 = reinterpret_cast<const float4*>(m0 + 80 + hh * 16);
        const float4* hb4 = reinterpret_cast<const float4*>(m1 + 80 + hh * 16);
#pragma unroll
        for (int i4 = 0; i4 < 4; ++i4) {
            const float4 va = ha4[i4];
            const float4 vb = hb4[i4];
            t0 = fmaf(va.x, w2c[4 * i4 + 0], t0);
            t1 = fmaf(vb.x, w2c[4 * i4 + 0], t1);
            t0 = fmaf(va.y, w2c[4 * i4 + 1], t0);
            t1 = fmaf(vb.y, w2c[4 * i4 + 1], t1);
            t0 = fmaf(va.z, w2c[4 * i4 + 2], t0);
            t1 = fmaf(vb.z, w2c[4 * i4 + 2], t1);
            t0 = fmaf(va.w, w2c[4 * i4 + 3], t0);
            t1 = fmaf(vb.w, w2c[4 * i4 + 3], t1);
        }
        t0 += __shfl_xor(t0, 32);
        t1 += __shfl_xor(t1, 32);
        t0 += b2o;
        t1 += b2o;

        if (lane < 32) {
            atomicAdd(&agg[(size_t)row0 * D + o], t0);
            atomicAdd(&agg[(size_t)row1 * D + o], t1);
        }
    }
}

__global__ __launch_bounds__(256) void node_kernel(
    const float* __restrict__ h, const float* __restrict__ agg,
    const float* __restrict__ Wd1, const float* __restrict__ bd1,
    const float* __restrict__ ln_g, const float* __restrict__ ln_b,
    const float* __restrict__ Wd2, const float* __restrict__ bd2,
    float* __restrict__ out)
{
    __shared__ float sWd1[64 * 32];
    __shared__ float sWd2[32 * 32];
    __shared__ float xbuf[4][64];

    for (int i = threadIdx.x; i < 64 * 32; i += 256) sWd1[i] = Wd1[i];
    for (int i = threadIdx.x; i < 32 * 32; i += 256) sWd2[i] = Wd2[i];
    __syncthreads();

    const int tid  = blockIdx.x * 256 + threadIdx.x;
    const int n    = tid >> 5;
    const int o    = tid & 31;
    const int wib  = threadIdx.x >> 6;
    const int lane = threadIdx.x & 63;
    if (n >= N_NODES) return;

    const float* hn = h   + (size_t)n * D;
    const float* an = agg + (size_t)n * D;

    // x[o] = [h | agg] . Wd1[:,o] + bd1[o]
    float x = bd1[o];
#pragma unroll
    for (int k4 = 0; k4 < 8; ++k4) {
        const float4 hv = *reinterpret_cast<const float4*>(hn + k4 * 4);
        x = fmaf(hv.x, sWd1[(k4 * 4 + 0) * 32 + o], x);
        x = fmaf(hv.y, sWd1[(k4 * 4 + 1) * 32 + o], x);
        x = fmaf(hv.z, sWd1[(k4 * 4 + 2) * 32 + o], x);
        x = fmaf(hv.w, sWd1[(k4 * 4 + 3) * 32 + o], x);
    }
#pragma unroll
    for (int k4 = 0; k4 < 8; ++k4) {
        const float4 av = *reinterpret_cast<const float4*>(an + k4 * 4);
        x = fmaf(av.x, sWd1[(32 + k4 * 4 + 0) * 32 + o], x);
        x = fmaf(av.y, sWd1[(32 + k4 * 4 + 1) * 32 + o], x);
        x = fmaf(av.z, sWd1[(32 + k4 * 4 + 2) * 32 + o], x);
        x = fmaf(av.w, sWd1[(32 + k4 * 4 + 3) * 32 + o], x);
    }

    // LayerNorm over the 32 lanes of this node
    float mu = x;
#pragma unroll
    for (int mm = 1; mm <= 16; mm <<= 1) mu += __shfl_xor(mu, mm);
    mu *= (1.0f / 32.0f);
    const float dx = x - mu;
    float var = dx * dx;
#pragma unroll
    for (int mm = 1; mm <= 16; mm <<= 1) var += __shfl_xor(var, mm);
    var *= (1.0f / 32.0f);
    float xs = dx * rsqrtf(var + 1e-5f);
    xs = xs * ln_g[o] + ln_b[o];
    // SiLU
    xs = xs / (1.0f + __expf(-xs));

    xbuf[wib][lane] = xs;

    // y[o] = xs . Wd2[:,o] + bd2[o]
    float y = bd2[o];
    const float* xb = &xbuf[wib][lane & 32];
#pragma unroll
    for (int k4 = 0; k4 < 8; ++k4) {
        const float4 xv = *reinterpret_cast<const float4*>(xb + k4 * 4);
        y = fmaf(xv.x, sWd2[(k4 * 4 + 0) * 32 + o], y);
        y = fmaf(xv.y, sWd2[(k4 * 4 + 1) * 32 + o], y);
        y = fmaf(xv.z, sWd2[(k4 * 4 + 2) * 32 + o], y);
        y = fmaf(xv.w, sWd2[(k4 * 4 + 3) * 32 + o], y);
    }
    out[(size_t)n * D + o] = tanhf(y);
}

extern "C" void kernel_launch(void* const* d_in, const int* in_sizes, int n_in,
                              void* d_out, int out_size, void* d_ws, size_t ws_size,
                              hipStream_t stream) {
    const float* h         = (const float*)d_in[1];
    const float* edge_attr = (const float*)d_in[2];
    const float* Q         = (const float*)d_in[3];
    const float* W1        = (const float*)d_in[4];
    const float* b1        = (const float*)d_in[5];
    const float* W2        = (const float*)d_in[6];
    const float* b2        = (const float*)d_in[7];
    const float* Wd1       = (const float*)d_in[8];
    const float* bd1       = (const float*)d_in[9];
    const float* ln_g      = (const float*)d_in[10];
    const float* ln_b      = (const float*)d_in[11];
    const float* Wd2       = (const float*)d_in[12];
    const float* bd2       = (const float*)d_in[13];
    const int*   eidx      = (const int*)d_in[14];

    float* agg = (float*)d_ws;
    hipMemsetAsync(agg, 0, (size_t)N_NODES * D * sizeof(float), stream);

    edge_kernel<<<2048, 256, 0, stream>>>(h, edge_attr, Q, W1, b1, W2, b2, eidx, agg);
    node_kernel<<<(N_NODES * D + 255) / 256, 256, 0, stream>>>(
        h, agg, Wd1, bd1, ln_g, ln_b, Wd2, bd2, (float*)d_out);
}

// Round 3
// 446.670 us; speedup vs baseline: 1.1202x; 1.1202x over previous
//
#include <hip/hip_runtime.h>
#include <math.h>

#define N_NODES 50000
#define E_EDGES 500000
#define D 32
#define ED 16
#define NBLK 2048
#define NW_TOTAL (NBLK * 4)

typedef float vf4 __attribute__((ext_vector_type(4)));

struct Stage {
    vf4 q0, q1, q2, q3;   // Q[e] rows k*8+g, cols sub*4..+3 (k=0..3)
    vf4 hc;               // h[col][sub*4..+3]
    vf4 st;               // staged: lanes<8 -> h[row] chunk, lanes 8..11 -> edge_attr chunk
};

__device__ __forceinline__ int2 ld_idx(const int* __restrict__ eidx, long long e) {
    int2 rc;
    rc.x = eidx[e];            // row
    rc.y = eidx[E_EDGES + e];  // col
    return rc;
}

__global__ __launch_bounds__(256) void edge_kernel(
    const float* __restrict__ h, const float* __restrict__ edge_attr,
    const float* __restrict__ Q, const float* __restrict__ W1,
    const float* __restrict__ b1, const float* __restrict__ W2,
    const float* __restrict__ b2, const int* __restrict__ eidx,
    float* __restrict__ agg)
{
    const int lane = threadIdx.x & 63;
    const int wib  = threadIdx.x >> 6;
    const int gwave = blockIdx.x * 4 + wib;

    const int o   = lane & 31;   // output unit
    const int hh  = lane >> 5;   // reduction half
    const int g   = lane >> 3;   // Q row group (0..7)
    const int sub = lane & 7;    // Q col chunk

    // --- W1 columns in registers, PERMUTED to match the LDS msg layout ---
    // LDS msg: [0..31]=h[row]; [32+g*4+k]=T[k*8+g]; [64..79]=edge_attr; [80..111]=hidden
    float w1c[40];
#pragma unroll
    for (int i = 0; i < 40; ++i) {
        const int p = hh * 40 + i;
        int f;
        if (p < 32)      f = p;
        else if (p < 64) f = 32 + ((p - 32) & 3) * 8 + ((p - 32) >> 2);
        else             f = p;
        w1c[i] = W1[f * D + o];
    }
    float w2c[16];
#pragma unroll
    for (int i = 0; i < 16; ++i) w2c[i] = W2[(hh * 16 + i) * D + o];
    const float b1o = b1[o];
    const float b2o = b2[o];

    __shared__ __align__(16) float msg_s[4][112];
    float* m = msg_s[wib];

    const long long nw = NW_TOTAL;
    long long e = gwave;
    int2 rcc = ld_idx(eidx, e);

    auto issue = [&](Stage& S, long long ee, int row, int col)
        __attribute__((always_inline)) {
        const float* qe = Q + (size_t)ee * (D * D);
        S.hc = *(const vf4*)(h + (size_t)col * D + sub * 4);
        if (lane < 12) {
            const float* gsrc = (lane < 8)
                ? (h + (size_t)row * D + lane * 4)
                : (edge_attr + (size_t)ee * ED + (lane - 8) * 4);
            S.st = *(const vf4*)gsrc;
        }
        S.q0 = __builtin_nontemporal_load((const vf4*)(qe + 0 * 256 + lane * 4));
        S.q1 = __builtin_nontemporal_load((const vf4*)(qe + 1 * 256 + lane * 4));
        S.q2 = __builtin_nontemporal_load((const vf4*)(qe + 2 * 256 + lane * 4));
        S.q3 = __builtin_nontemporal_load((const vf4*)(qe + 3 * 256 + lane * 4));
    };

    auto compute = [&](const Stage& S, int row)
        __attribute__((always_inline)) {
        // T14 write-late: park staged h[row]/edge_attr into LDS
        if (lane < 12) {
            float* dst = (lane < 8) ? (m + lane * 4) : (m + 64 + (lane - 8) * 4);
            *(vf4*)dst = S.st;
        }
        // sheaf transport partials
        float a0 = S.q0.x * S.hc.x + S.q0.y * S.hc.y + S.q0.z * S.hc.z + S.q0.w * S.hc.w;
        float a1 = S.q1.x * S.hc.x + S.q1.y * S.hc.y + S.q1.z * S.hc.z + S.q1.w * S.hc.w;
        float a2 = S.q2.x * S.hc.x + S.q2.y * S.hc.y + S.q2.z * S.hc.z + S.q2.w * S.hc.w;
        float a3 = S.q3.x * S.hc.x + S.q3.y * S.hc.y + S.q3.z * S.hc.z + S.q3.w * S.hc.w;
#pragma unroll
        for (int mm = 1; mm <= 4; mm <<= 1) {
            a0 += __shfl_xor(a0, mm);
            a1 += __shfl_xor(a1, mm);
            a2 += __shfl_xor(a2, mm);
            a3 += __shfl_xor(a3, mm);
        }
        if (sub == 0) {
            vf4 t; t.x = a0; t.y = a1; t.z = a2; t.w = a3;
            *(vf4*)(m + 32 + g * 4) = t;   // permuted layout, matches w1c
        }
        // MLP layer 1 (broadcast ds_read_b128; weights in regs)
        float s = 0.f;
        const vf4* mv = (const vf4*)(m + hh * 40);
#pragma unroll
        for (int i4 = 0; i4 < 10; ++i4) {
            const vf4 v = mv[i4];
            s = fmaf(v.x, w1c[4 * i4 + 0], s);
            s = fmaf(v.y, w1c[4 * i4 + 1], s);
            s = fmaf(v.z, w1c[4 * i4 + 2], s);
            s = fmaf(v.w, w1c[4 * i4 + 3], s);
        }
        s += __shfl_xor(s, 32);
        s = fmaxf(s + b1o, 0.f);
        if (lane < 32) m[80 + o] = s;
        // MLP layer 2
        float t = 0.f;
        const vf4* hv = (const vf4*)(m + 80 + hh * 16);
#pragma unroll
        for (int i4 = 0; i4 < 4; ++i4) {
            const vf4 v = hv[i4];
            t = fmaf(v.x, w2c[4 * i4 + 0], t);
            t = fmaf(v.y, w2c[4 * i4 + 1], t);
            t = fmaf(v.z, w2c[4 * i4 + 2], t);
            t = fmaf(v.w, w2c[4 * i4 + 3], t);
        }
        t += __shfl_xor(t, 32);
        t += b2o;
        if (lane < 32) atomicAdd(&agg[(size_t)row * D + o], t);
    };

    // ---- prologue: fill both pipeline stages ----
    const long long e1 = e + nw;
    int2 rcn = make_int2(0, 0);
    if (e1 < E_EDGES) rcn = ld_idx(eidx, e1);

    Stage A, B;
    issue(A, e, rcc.x, rcc.y);
    if (e1 < E_EDGES) issue(B, e1, rcn.x, rcn.y);

    // ---- steady state: { idx(t+2); compute(t); issue(t+2) } ----
    while (true) {
        {   // body A (edge e)
            const long long e2 = e + 2 * nw;
            int2 rc2 = make_int2(0, 0);
            if (e2 < E_EDGES) rc2 = ld_idx(eidx, e2);
            compute(A, rcc.x);
            if (e2 < E_EDGES) issue(A, e2, rc2.x, rc2.y);
            rcc = rcn; rcn = rc2;
            e += nw;
            if (e >= E_EDGES) break;
        }
        {   // body B (edge e)
            const long long e2 = e + 2 * nw;
            int2 rc2 = make_int2(0, 0);
            if (e2 < E_EDGES) rc2 = ld_idx(eidx, e2);
            compute(B, rcc.x);
            if (e2 < E_EDGES) issue(B, e2, rc2.x, rc2.y);
            rcc = rcn; rcn = rc2;
            e += nw;
            if (e >= E_EDGES) break;
        }
    }
}

__global__ __launch_bounds__(256) void node_kernel(
    const float* __restrict__ h, const float* __restrict__ agg,
    const float* __restrict__ Wd1, const float* __restrict__ bd1,
    const float* __restrict__ ln_g, const float* __restrict__ ln_b,
    const float* __restrict__ Wd2, const float* __restrict__ bd2,
    float* __restrict__ out)
{
    __shared__ float sWd1[64 * 32];
    __shared__ float sWd2[32 * 32];
    __shared__ float xbuf[4][64];

    for (int i = threadIdx.x; i < 64 * 32; i += 256) sWd1[i] = Wd1[i];
    for (int i = threadIdx.x; i < 32 * 32; i += 256) sWd2[i] = Wd2[i];
    __syncthreads();

    const int tid  = blockIdx.x * 256 + threadIdx.x;
    const int n    = tid >> 5;
    const int o    = tid & 31;
    const int wib  = threadIdx.x >> 6;
    const int lane = threadIdx.x & 63;
    if (n >= N_NODES) return;

    const float* hn = h   + (size_t)n * D;
    const float* an = agg + (size_t)n * D;

    float x = bd1[o];
#pragma unroll
    for (int k4 = 0; k4 < 8; ++k4) {
        const float4 hv = *reinterpret_cast<const float4*>(hn + k4 * 4);
        x = fmaf(hv.x, sWd1[(k4 * 4 + 0) * 32 + o], x);
        x = fmaf(hv.y, sWd1[(k4 * 4 + 1) * 32 + o], x);
        x = fmaf(hv.z, sWd1[(k4 * 4 + 2) * 32 + o], x);
        x = fmaf(hv.w, sWd1[(k4 * 4 + 3) * 32 + o], x);
    }
#pragma unroll
    for (int k4 = 0; k4 < 8; ++k4) {
        const float4 av = *reinterpret_cast<const float4*>(an + k4 * 4);
        x = fmaf(av.x, sWd1[(32 + k4 * 4 + 0) * 32 + o], x);
        x = fmaf(av.y, sWd1[(32 + k4 * 4 + 1) * 32 + o], x);
        x = fmaf(av.z, sWd1[(32 + k4 * 4 + 2) * 32 + o], x);
        x = fmaf(av.w, sWd1[(32 + k4 * 4 + 3) * 32 + o], x);
    }

    float mu = x;
#pragma unroll
    for (int mm = 1; mm <= 16; mm <<= 1) mu += __shfl_xor(mu, mm);
    mu *= (1.0f / 32.0f);
    const float dx = x - mu;
    float var = dx * dx;
#pragma unroll
    for (int mm = 1; mm <= 16; mm <<= 1) var += __shfl_xor(var, mm);
    var *= (1.0f / 32.0f);
    float xs = dx * rsqrtf(var + 1e-5f);
    xs = xs * ln_g[o] + ln_b[o];
    xs = xs / (1.0f + __expf(-xs));

    xbuf[wib][lane] = xs;

    float y = bd2[o];
    const float* xb = &xbuf[wib][lane & 32];
#pragma unroll
    for (int k4 = 0; k4 < 8; ++k4) {
        const float4 xv = *reinterpret_cast<const float4*>(xb + k4 * 4);
        y = fmaf(xv.x, sWd2[(k4 * 4 + 0) * 32 + o], y);
        y = fmaf(xv.y, sWd2[(k4 * 4 + 1) * 32 + o], y);
        y = fmaf(xv.z, sWd2[(k4 * 4 + 2) * 32 + o], y);
        y = fmaf(xv.w, sWd2[(k4 * 4 + 3) * 32 + o], y);
    }
    out[(size_t)n * D + o] = tanhf(y);
}

extern "C" void kernel_launch(void* const* d_in, const int* in_sizes, int n_in,
                              void* d_out, int out_size, void* d_ws, size_t ws_size,
                              hipStream_t stream) {
    const float* h         = (const float*)d_in[1];
    const float* edge_attr = (const float*)d_in[2];
    const float* Q         = (const float*)d_in[3];
    const float* W1        = (const float*)d_in[4];
    const float* b1        = (const float*)d_in[5];
    const float* W2        = (const float*)d_in[6];
    const float* b2        = (const float*)d_in[7];
    const float* Wd1       = (const float*)d_in[8];
    const float* bd1       = (const float*)d_in[9];
    const float* ln_g      = (const float*)d_in[10];
    const float* ln_b      = (const float*)d_in[11];
    const float* Wd2       = (const float*)d_in[12];
    const float* bd2       = (const float*)d_in[13];
    const int*   eidx      = (const int*)d_in[14];

    float* agg = (float*)d_ws;
    hipMemsetAsync(agg, 0, (size_t)N_NODES * D * sizeof(float), stream);

    edge_kernel<<<NBLK, 256, 0, stream>>>(h, edge_attr, Q, W1, b1, W2, b2, eidx, agg);
    node_kernel<<<(N_NODES * D + 255) / 256, 256, 0, stream>>>(
        h, agg, Wd1, bd1, ln_g, ln_b, Wd2, bd2, (float*)d_out);
}